// Round 4
// baseline (495.411 us; speedup 1.0000x reference)
//
#include <hip/hip_runtime.h>

typedef __bf16 bf16_t;
typedef bf16_t bf16x8 __attribute__((ext_vector_type(8)));
typedef float f32x4 __attribute__((ext_vector_type(4)));
typedef unsigned short u16;

#define MFMA16 __builtin_amdgcn_mfma_f32_16x16x32_bf16

#define NT_TOK   12288           // tokens per batch (L*N)
#define T_TOK    49152           // total tokens
#define NWELT    163840          // 160*1024 packed W elements
#define NMELT    196608          // 128*1536 mem elements

// workspace layout (bytes), all 16B aligned
#define WS_PC    0               // float[T_TOK*128]   pc (biased, fp32)
#define WS_S     25165824        // float[T_TOK*24]    seg softmax
#define WS_WB    29884416        // u16[160*1024]      packed seg_w|pc_w bf16
#define WS_MEMF  30212096        // u16[128*1536]      mem bf16 (row-major: [f][slot])
#define WS_MEMT  30605312        // u16[1536*128]      mem^T bf16 ([slot][d])
#define WS_SKL   30998528        // float[512]         per-(b,f) running max
#define WS_LOSS  31000576        // float[1]

__device__ __forceinline__ u16 f2bf(float f) {
  union { bf16_t h; u16 u; } c; c.h = (bf16_t)f; return c.u;
}

__device__ __forceinline__ void atomic_max_f32(float* a, float v) {
  if (v >= 0.f) atomicMax((int*)a, __float_as_int(v));
  else atomicMin((unsigned int*)a, (unsigned int)__float_as_int(v));
}

// ---------------- init: pack weights/mem to bf16, init reductions ----------
__global__ void k_init(const float* __restrict__ seg_w, const float* __restrict__ pc_w,
                       const float* __restrict__ mem,
                       u16* __restrict__ Wb, u16* __restrict__ memF, u16* __restrict__ memT,
                       float* __restrict__ skl, float* __restrict__ loss)
{
  int i = blockIdx.x * 256 + threadIdx.x;
  if (i < NWELT) {
    int row = i >> 10, k = i & 1023;
    float v = 0.f;
    if (row < 24) v = seg_w[(row << 10) + k];
    else if (row < 152) v = pc_w[((row - 24) << 10) + k];
    Wb[i] = f2bf(v);
  } else if ((i -= NWELT) < NMELT) {
    memF[i] = f2bf(mem[i]);
  } else if ((i -= NMELT) < NMELT) {
    int slot = i >> 7, d = i & 127;
    memT[i] = f2bf(mem[d * 1536 + slot]);
  } else if ((i -= NMELT) < 512) {
    skl[i] = -__builtin_inff();
  } else if (i == 512) {
    *loss = 0.f;
  }
}

// ------- projection: 64 tok/block, 768 blocks (3/CU), no LDS, no barriers,
//         4-deep register prefetch on the feat stream (HBM-bound by design)
__global__ __launch_bounds__(256, 3) void k_proj(
    const float* __restrict__ feat, const u16* __restrict__ Wb,
    const float* __restrict__ seg_b, const float* __restrict__ pc_b,
    float* __restrict__ pc_out, float* __restrict__ s_out, float* __restrict__ out_seg)
{
  const int tid = threadIdx.x;
  const int w = tid >> 6;
  const int lane = tid & 63;
  const int n = lane & 15;
  const int q = lane >> 4;
  const int base = blockIdx.x * 64;

  f32x4 acc[10];
  #pragma unroll
  for (int t = 0; t < 10; ++t) acc[t] = (f32x4){0.f, 0.f, 0.f, 0.f};

  const float* fp0 = feat + (size_t)(base + w * 16 + n) * 1024 + q * 8;
  const u16* wp = Wb + (size_t)n * 1024 + q * 8;

  // rolling register prefetch buffer, depth 4 (static indices via full unroll)
  float4 fb[4][2];
  #pragma unroll
  for (int p = 0; p < 4; ++p) {
    const float4* a = (const float4*)(fp0 + p * 32);
    fb[p][0] = a[0];
    fb[p][1] = a[1];
  }

  for (int kb = 0; kb < 8; ++kb) {
    #pragma unroll
    for (int p = 0; p < 4; ++p) {
      const int kc = kb * 4 + p;
      // consume prefetched feat
      float4 x0 = fb[p][0], y0 = fb[p][1];
      // W B-frags direct from global (10 KB working set, L1-resident)
      bf16x8 bw[10];
      #pragma unroll
      for (int t = 0; t < 10; ++t)
        bw[t] = *(const bf16x8*)(wp + (size_t)t * 16384 + kc * 32);
      // issue next prefetch (stays in flight across the MFMAs)
      if (kb < 7) {
        const float4* a = (const float4*)(fp0 + (kc + 4) * 32);
        fb[p][0] = a[0];
        fb[p][1] = a[1];
      }
      bf16x8 af;
      af[0] = (bf16_t)x0.x; af[1] = (bf16_t)x0.y; af[2] = (bf16_t)x0.z; af[3] = (bf16_t)x0.w;
      af[4] = (bf16_t)y0.x; af[5] = (bf16_t)y0.y; af[6] = (bf16_t)y0.z; af[7] = (bf16_t)y0.w;
      #pragma unroll
      for (int t = 0; t < 10; ++t)
        acc[t] = MFMA16(af, bw[t], acc[t], 0, 0, 0);
    }
  }

  // epilogue: seg softmax (cols 0..23) + biased pc (cols 24..151)
  #pragma unroll
  for (int r = 0; r < 4; ++r) {
    const int token = base + w * 16 + q * 4 + r;
    float v0 = acc[0][r] + seg_b[n];
    float v1 = (n < 8) ? (acc[1][r] + seg_b[16 + n]) : -__builtin_inff();
    float mx = fmaxf(v0, v1);
    #pragma unroll
    for (int d2 = 1; d2 < 16; d2 <<= 1) mx = fmaxf(mx, __shfl_xor(mx, d2, 16));
    float e0 = __expf(v0 - mx);
    float e1 = (n < 8) ? __expf(v1 - mx) : 0.f;
    float sm = e0 + e1;
    #pragma unroll
    for (int d2 = 1; d2 < 16; d2 <<= 1) sm += __shfl_xor(sm, d2, 16);
    float is = 1.f / sm;
    float s0v = e0 * is, s1v = e1 * is;
    s_out[(size_t)token * 24 + n] = s0v;
    if (n < 8) s_out[(size_t)token * 24 + 16 + n] = s1v;
    const int b = token / NT_TOK;
    const int rem = token - b * NT_TOK;
    const int l = rem >> 9, p = rem & 511;
    float* so = out_seg + ((size_t)(b * 24 + l) * 24) * 512 + p;
    so[(size_t)n * 512] = s0v;
    if (n < 8) so[(size_t)(16 + n) * 512] = s1v;
    #pragma unroll
    for (int t = 1; t < 10; ++t) {
      int col = t * 16 + n;
      if (col >= 24 && col < 152) {
        pc_out[(size_t)token * 128 + (col - 24)] = acc[t][r] + pc_b[col - 24];
      }
    }
  }
}

// ------- attention v3: no max-tracking (logits bounded), slot/f wave split,
//         mem frags direct from global (L1/L2), LDS only for P + reductions
#define AS_S     0                     // float[64][26]   = 6656
#define AS_P     6656                  // u16[64][72]     = 9216
#define AS_LW    15872                 // float[4][64]    = 1024
#define AS_RL    16896                 // float[4]
#define AS_TOT   16912

__global__ __launch_bounds__(256, 3) void k_attn(
    const float* __restrict__ pc, const float* __restrict__ s_in,
    const u16* __restrict__ memF, const u16* __restrict__ memT,
    float* __restrict__ skl, float* __restrict__ loss)
{
  __shared__ __align__(16) char smem[AS_TOT];
  float* s_tile = (float*)(smem + AS_S);        // [64][26] padded
  u16* Pl  = (u16*)(smem + AS_P);               // [64 tok][72] (block-shared)
  float* lw  = (float*)(smem + AS_LW);          // per-wave l partials [4][64]
  float* redL = (float*)(smem + AS_RL);

  const int tid = threadIdx.x;
  const int w = tid >> 6, lane = tid & 63, n = lane & 15, q = lane >> 4;
  const int base = blockIdx.x * 64;

  for (int i = tid; i < 1536; i += 256) {
    int t = i / 24, jj = i - t * 24;
    s_tile[t * 26 + jj] = s_in[(size_t)base * 24 + i];
  }

  // Q fragments (64 tokens, B-operand layout) straight from global pc
  bf16x8 qf[4][4];                     // [tok-tile][ks]
  #pragma unroll
  for (int tt = 0; tt < 4; ++tt)
    #pragma unroll
    for (int ks = 0; ks < 4; ++ks) {
      const float4* qp = (const float4*)(pc + (size_t)(base + tt * 16 + n) * 128 + ks * 32 + q * 8);
      float4 x = qp[0], y = qp[1];
      bf16x8 a;
      a[0] = (bf16_t)x.x; a[1] = (bf16_t)x.y; a[2] = (bf16_t)x.z; a[3] = (bf16_t)x.w;
      a[4] = (bf16_t)y.x; a[5] = (bf16_t)y.y; a[6] = (bf16_t)y.z; a[7] = (bf16_t)y.w;
      qf[tt][ks] = a;
    }

  f32x4 o[4][2];                       // [tok-tile][f-tile], f = w*32 + ft*16 + n
  #pragma unroll
  for (int tt = 0; tt < 4; ++tt) {
    o[tt][0] = (f32x4){0.f, 0.f, 0.f, 0.f};
    o[tt][1] = (f32x4){0.f, 0.f, 0.f, 0.f};
  }
  float l_acc[4] = {0.f, 0.f, 0.f, 0.f};   // per tok-tile, partial over this wave's slots

  const float invs = 0.088388347648318447f; // 1/sqrt(128)
  __syncthreads();                          // s_tile ready

  for (int j = 0; j < 24; ++j) {
    // S^T tile: this wave owns slots [w*16, w*16+16) x 64 tokens
    // A = memT rows (slot-major), direct global; B = qf
    f32x4 sacc[4];
    #pragma unroll
    for (int tt = 0; tt < 4; ++tt) sacc[tt] = (f32x4){0.f, 0.f, 0.f, 0.f};
    #pragma unroll
    for (int ks = 0; ks < 4; ++ks) {
      bf16x8 am = *(const bf16x8*)(memT + (size_t)(j * 64 + w * 16 + n) * 128 + ks * 32 + q * 8);
      #pragma unroll
      for (int tt = 0; tt < 4; ++tt)
        sacc[tt] = MFMA16(am, qf[tt][ks], sacc[tt], 0, 0, 0);
    }

    __syncthreads();   // previous chunk's PV reads of Pl are done
    // p = exp(s * seg/sqrt(D)) without max subtraction (logits bounded ~|4|)
    #pragma unroll
    for (int tt = 0; tt < 4; ++tt) {
      float sj = s_tile[(tt * 16 + n) * 26 + j] * invs;
      float p0 = __expf(sacc[tt][0] * sj);
      float p1 = __expf(sacc[tt][1] * sj);
      float p2 = __expf(sacc[tt][2] * sj);
      float p3 = __expf(sacc[tt][3] * sj);
      l_acc[tt] += (p0 + p1) + (p2 + p3);
      ushort4 pk;
      pk.x = f2bf(p0); pk.y = f2bf(p1); pk.z = f2bf(p2); pk.w = f2bf(p3);
      *(ushort4*)(&Pl[(tt * 16 + n) * 72 + w * 16 + q * 4]) = pk;
    }
    __syncthreads();   // P visible to all waves

    // PV: this wave owns f in [w*32, w*32+32) x 64 tokens
    // A = P rows (tok-major, LDS); B = memF rows (f-major), direct global
    #pragma unroll
    for (int h = 0; h < 2; ++h) {
      bf16x8 bm[2];
      #pragma unroll
      for (int ft = 0; ft < 2; ++ft)
        bm[ft] = *(const bf16x8*)(memF + (size_t)(w * 32 + ft * 16 + n) * 1536 + j * 64 + h * 32 + q * 8);
      #pragma unroll
      for (int tt = 0; tt < 4; ++tt) {
        bf16x8 pa = *(const bf16x8*)(&Pl[(tt * 16 + n) * 72 + h * 32 + q * 8]);
        o[tt][0] = MFMA16(pa, bm[0], o[tt][0], 0, 0, 0);
        o[tt][1] = MFMA16(pa, bm[1], o[tt][1], 0, 0, 0);
      }
    }
  }

  // l reduction: per-wave partials (sum over q) -> LDS -> sum over waves
  #pragma unroll
  for (int tt = 0; tt < 4; ++tt) {
    float v = l_acc[tt];
    v += __shfl_xor(v, 16, 64);
    v += __shfl_xor(v, 32, 64);
    if (q == 0) lw[w * 64 + tt * 16 + n] = v;
  }
  __syncthreads();

  // epilogue: rec = O/l, loss partial, per-f max
  float lsum = 0.f;
  float fmax2[2] = {-__builtin_inff(), -__builtin_inff()};
  #pragma unroll
  for (int tt = 0; tt < 4; ++tt) {
    f32x4 linv;
    #pragma unroll
    for (int r = 0; r < 4; ++r) {
      int tok = tt * 16 + q * 4 + r;
      float lt = lw[tok] + lw[64 + tok] + lw[128 + tok] + lw[192 + tok];
      linv[r] = 1.f / lt;
    }
    #pragma unroll
    for (int ft = 0; ft < 2; ++ft)
      #pragma unroll
      for (int r = 0; r < 4; ++r) {
        const int token = base + tt * 16 + q * 4 + r;
        const int f = w * 32 + ft * 16 + n;
        float rec = o[tt][ft][r] * linv[r];
        float d = rec - pc[(size_t)token * 128 + f];
        lsum += d * d;
        fmax2[ft] = fmaxf(fmax2[ft], rec);
      }
  }
  #pragma unroll
  for (int ft = 0; ft < 2; ++ft) {
    float v = fmax2[ft];
    v = fmaxf(v, __shfl_xor(v, 16, 64));
    v = fmaxf(v, __shfl_xor(v, 32, 64));
    if (q == 0) atomic_max_f32(&skl[(base / NT_TOK) * 128 + w * 32 + ft * 16 + n], v);
  }
  #pragma unroll
  for (int d2 = 1; d2 < 64; d2 <<= 1) lsum += __shfl_xor(lsum, d2, 64);
  if (lane == 0) redL[w] = lsum;
  __syncthreads();
  if (tid == 0) atomicAdd(loss, redL[0] + redL[1] + redL[2] + redL[3]);
}

// ---------------- head: LN -> Linear -> GELU -> Linear + loss finalize -----
__global__ void k_head(const float* __restrict__ skl,
                       const float* __restrict__ ln_g, const float* __restrict__ ln_b,
                       const float* __restrict__ w1, const float* __restrict__ b1,
                       const float* __restrict__ w2, const float* __restrict__ b2,
                       const float* __restrict__ loss, float* __restrict__ out)
{
  __shared__ float hbuf[128];
  __shared__ float gbuf[64];
  __shared__ float red[4];
  const int t = threadIdx.x;            // 128 threads
  const int ln = t & 63, wv = t >> 6;
  for (int b = 0; b < 4; ++b) {
    float x = skl[b * 128 + t];
    float s1 = x, s2 = x * x;
    #pragma unroll
    for (int d = 1; d < 64; d <<= 1) {
      s1 += __shfl_xor(s1, d, 64);
      s2 += __shfl_xor(s2, d, 64);
    }
    if (ln == 0) { red[wv * 2] = s1; red[wv * 2 + 1] = s2; }
    __syncthreads();
    float mu = (red[0] + red[2]) * (1.f / 128.f);
    float var = (red[1] + red[3]) * (1.f / 128.f) - mu * mu;
    float hn = (x - mu) * rsqrtf(var + 1e-5f) * ln_g[t] + ln_b[t];
    hbuf[t] = hn;
    __syncthreads();
    if (t < 64) {
      float a = b1[t];
      for (int c = 0; c < 128; ++c) a += hbuf[c] * w1[t * 128 + c];
      gbuf[t] = 0.5f * a * (1.f + erff(a * 0.70710678118654752f));
    }
    __syncthreads();
    if (t < 72) {
      float a = b2[t];
      for (int c = 0; c < 64; ++c) a += gbuf[c] * w2[t * 64 + c];
      out[b * 72 + t] = a;
    }
    __syncthreads();
  }
  if (t == 0) out[1179936] = loss[0] * (1.f / 6291456.f);
}

extern "C" void kernel_launch(void* const* d_in, const int* in_sizes, int n_in,
                              void* d_out, int out_size, void* d_ws, size_t ws_size,
                              hipStream_t stream) {
  (void)in_sizes; (void)n_in; (void)out_size; (void)ws_size;
  const float* feat  = (const float*)d_in[0];
  const float* seg_w = (const float*)d_in[1];
  const float* seg_b = (const float*)d_in[2];
  const float* pc_w  = (const float*)d_in[3];
  const float* pc_b  = (const float*)d_in[4];
  const float* mem   = (const float*)d_in[5];
  const float* ln_g  = (const float*)d_in[6];
  const float* ln_b  = (const float*)d_in[7];
  const float* w1    = (const float*)d_in[8];
  const float* b1    = (const float*)d_in[9];
  const float* w2    = (const float*)d_in[10];
  const float* b2    = (const float*)d_in[11];

  char* ws = (char*)d_ws;
  float* pc_buf = (float*)(ws + WS_PC);
  float* s_buf  = (float*)(ws + WS_S);
  u16*   Wb     = (u16*)(ws + WS_WB);
  u16*   memFb  = (u16*)(ws + WS_MEMF);
  u16*   memTb  = (u16*)(ws + WS_MEMT);
  float* sklb   = (float*)(ws + WS_SKL);
  float* lossb  = (float*)(ws + WS_LOSS);
  float* out    = (float*)d_out;

  k_init<<<2179, 256, 0, stream>>>(seg_w, pc_w, mem, Wb, memFb, memTb, sklb, lossb);
  k_proj<<<768, 256, 0, stream>>>(feat, Wb, seg_b, pc_b, pc_buf, s_buf, out + 288);
  k_attn<<<768, 256, 0, stream>>>(pc_buf, s_buf, memFb, memTb, sklb, lossb);
  k_head<<<1, 128, 0, stream>>>(sklb, ln_g, ln_b, w1, b1, w2, b2, lossb, out);
}

// Round 5
// 417.199 us; speedup vs baseline: 1.1875x; 1.1875x over previous
//
#include <hip/hip_runtime.h>

typedef __bf16 bf16_t;
typedef bf16_t bf16x8 __attribute__((ext_vector_type(8)));
typedef float f32x4 __attribute__((ext_vector_type(4)));
typedef unsigned short u16;

#define MFMA16 __builtin_amdgcn_mfma_f32_16x16x32_bf16

#define NT_TOK   12288           // tokens per batch (L*N)
#define T_TOK    49152           // total tokens

// workspace layout (bytes), all 16B aligned
#define WS_PC    0               // float[T_TOK*128]   pc (biased, fp32)
#define WS_S     25165824        // float[T_TOK*24]    seg softmax
#define WS_WP    29884416        // u16[32*10*64*8]    W frags, lane-packed (320 KB)
#define WS_MTP   30212096        // u16[24*16*64*8]    memT frags, lane-packed (384 KB)
#define WS_MFP   30605312        // u16[24*16*64*8]    memF frags, lane-packed (384 KB)
#define WS_SKL   30998528        // float[512]         per-(b,f) running max
#define WS_LOSS  31000576        // float[1]

__device__ __forceinline__ u16 f2bf(float f) {
  union { bf16_t h; u16 u; } c; c.h = (bf16_t)f; return c.u;
}

__device__ __forceinline__ void atomic_max_f32(float* a, float v) {
  if (v >= 0.f) atomicMax((int*)a, __float_as_int(v));
  else atomicMin((unsigned int*)a, (unsigned int)__float_as_int(v));
}

// ---- init: pack W / memT / memF into fragment-major lane order ------------
// Each thread produces one 16 B unit (8 bf16) = exactly what one lane of one
// wave will load in the hot loops (so hot-loop loads are lane-contiguous).
__global__ void k_init(const float* __restrict__ seg_w, const float* __restrict__ pc_w,
                       const float* __restrict__ mem,
                       u16* __restrict__ Wp, u16* __restrict__ mTp, u16* __restrict__ mFp,
                       float* __restrict__ skl, float* __restrict__ loss)
{
  int i = blockIdx.x * 256 + threadIdx.x;
  union { u16 s[8]; uint4 v; } u;
  if (i < 20480) {                       // W: unit = (kc*10 + t)*64 + lane
    int lane = i & 63, blk = i >> 6;
    int kc = blk / 10, t = blk - kc * 10;
    int n = lane & 15, q = lane >> 4;
    int row = t * 16 + n;
    int k0 = kc * 32 + q * 8;
    #pragma unroll
    for (int e = 0; e < 8; ++e) {
      float v = 0.f;
      if (row < 24) v = seg_w[row * 1024 + k0 + e];
      else if (row < 152) v = pc_w[(row - 24) * 1024 + k0 + e];
      u.s[e] = f2bf(v);
    }
    *(uint4*)(Wp + (size_t)i * 8) = u.v;
  } else if ((i -= 20480) < 24576) {     // memT: unit = (j*16 + wv*4 + ks)*64 + lane
    int lane = i & 63, blk = i >> 6;
    int j = blk >> 4, rem = blk & 15, wv = rem >> 2, ks = rem & 3;
    int n = lane & 15, q = lane >> 4;
    int slot = j * 64 + wv * 16 + n;
    int d0 = ks * 32 + q * 8;
    #pragma unroll
    for (int e = 0; e < 8; ++e)
      u.s[e] = f2bf(mem[(size_t)(d0 + e) * 1536 + slot]);
    *(uint4*)(mTp + (size_t)i * 8) = u.v;
  } else if ((i -= 24576) < 24576) {     // memF: unit = (j*16 + h*8 + wv*2 + ft)*64 + lane
    int lane = i & 63, blk = i >> 6;
    int j = blk >> 4, h = (blk >> 3) & 1, wv = (blk >> 1) & 3, ft = blk & 1;
    int n = lane & 15, q = lane >> 4;
    int f = wv * 32 + ft * 16 + n;
    int s0 = j * 64 + h * 32 + q * 8;
    #pragma unroll
    for (int e = 0; e < 8; ++e)
      u.s[e] = f2bf(mem[(size_t)f * 1536 + s0 + e]);
    *(uint4*)(mFp + (size_t)i * 8) = u.v;
  } else if ((i -= 24576) < 512) {
    skl[i] = -__builtin_inff();
  } else if (i == 512) {
    *loss = 0.f;
  }
}

// ------- projection: 64 tok/block, 768 blocks (3/CU), no LDS, no barriers.
//         feat: 4-deep register prefetch; W: lane-packed coalesced frags.
__global__ __launch_bounds__(256, 3) void k_proj(
    const float* __restrict__ feat, const u16* __restrict__ Wp,
    const float* __restrict__ seg_b, const float* __restrict__ pc_b,
    float* __restrict__ pc_out, float* __restrict__ s_out, float* __restrict__ out_seg)
{
  const int tid = threadIdx.x;
  const int w = tid >> 6;
  const int lane = tid & 63;
  const int n = lane & 15;
  const int q = lane >> 4;
  const int base = blockIdx.x * 64;

  f32x4 acc[10];
  #pragma unroll
  for (int t = 0; t < 10; ++t) acc[t] = (f32x4){0.f, 0.f, 0.f, 0.f};

  const float* fp0 = feat + (size_t)(base + w * 16 + n) * 1024 + q * 8;
  const u16* wfrag = Wp + (size_t)lane * 8;   // + (kc*10 + t)*512

  // rolling register prefetch buffer, depth 4 (static indices via full unroll)
  float4 fb[4][2];
  #pragma unroll
  for (int p = 0; p < 4; ++p) {
    const float4* a = (const float4*)(fp0 + p * 32);
    fb[p][0] = a[0];
    fb[p][1] = a[1];
  }

  for (int kb = 0; kb < 8; ++kb) {
    #pragma unroll
    for (int p = 0; p < 4; ++p) {
      const int kc = kb * 4 + p;
      float4 x0 = fb[p][0], y0 = fb[p][1];
      // W frags: lane-contiguous 1 KB per instruction, L1-resident
      bf16x8 bw[10];
      #pragma unroll
      for (int t = 0; t < 10; ++t)
        bw[t] = *(const bf16x8*)(wfrag + (size_t)(kc * 10 + t) * 512);
      if (kb < 7) {
        const float4* a = (const float4*)(fp0 + (kc + 4) * 32);
        fb[p][0] = a[0];
        fb[p][1] = a[1];
      }
      bf16x8 af;
      af[0] = (bf16_t)x0.x; af[1] = (bf16_t)x0.y; af[2] = (bf16_t)x0.z; af[3] = (bf16_t)x0.w;
      af[4] = (bf16_t)y0.x; af[5] = (bf16_t)y0.y; af[6] = (bf16_t)y0.z; af[7] = (bf16_t)y0.w;
      #pragma unroll
      for (int t = 0; t < 10; ++t)
        acc[t] = MFMA16(af, bw[t], acc[t], 0, 0, 0);
    }
  }

  // epilogue: seg softmax (cols 0..23) + biased pc (cols 24..151)
  #pragma unroll
  for (int r = 0; r < 4; ++r) {
    const int token = base + w * 16 + q * 4 + r;
    float v0 = acc[0][r] + seg_b[n];
    float v1 = (n < 8) ? (acc[1][r] + seg_b[16 + n]) : -__builtin_inff();
    float mx = fmaxf(v0, v1);
    #pragma unroll
    for (int d2 = 1; d2 < 16; d2 <<= 1) mx = fmaxf(mx, __shfl_xor(mx, d2, 16));
    float e0 = __expf(v0 - mx);
    float e1 = (n < 8) ? __expf(v1 - mx) : 0.f;
    float sm = e0 + e1;
    #pragma unroll
    for (int d2 = 1; d2 < 16; d2 <<= 1) sm += __shfl_xor(sm, d2, 16);
    float is = 1.f / sm;
    float s0v = e0 * is, s1v = e1 * is;
    s_out[(size_t)token * 24 + n] = s0v;
    if (n < 8) s_out[(size_t)token * 24 + 16 + n] = s1v;
    const int b = token / NT_TOK;
    const int rem = token - b * NT_TOK;
    const int l = rem >> 9, p = rem & 511;
    float* so = out_seg + ((size_t)(b * 24 + l) * 24) * 512 + p;
    so[(size_t)n * 512] = s0v;
    if (n < 8) so[(size_t)(16 + n) * 512] = s1v;
    #pragma unroll
    for (int t = 1; t < 10; ++t) {
      int col = t * 16 + n;
      if (col >= 24 && col < 152) {
        pc_out[(size_t)token * 128 + (col - 24)] = acc[t][r] + pc_b[col - 24];
      }
    }
  }
}

// ------- attention: no max-tracking, slot/f wave split, lane-packed mem ----
#define AS_S     0                     // float[64][26]   = 6656
#define AS_P     6656                  // u16[64][72]     = 9216
#define AS_LW    15872                 // float[4][64]    = 1024
#define AS_RL    16896                 // float[4]
#define AS_TOT   16912

__global__ __launch_bounds__(256, 3) void k_attn(
    const float* __restrict__ pc, const float* __restrict__ s_in,
    const u16* __restrict__ mFp, const u16* __restrict__ mTp,
    float* __restrict__ skl, float* __restrict__ loss)
{
  __shared__ __align__(16) char smem[AS_TOT];
  float* s_tile = (float*)(smem + AS_S);        // [64][26] padded
  u16* Pl  = (u16*)(smem + AS_P);               // [64 tok][72] (block-shared)
  float* lw  = (float*)(smem + AS_LW);          // per-wave l partials [4][64]
  float* redL = (float*)(smem + AS_RL);

  const int tid = threadIdx.x;
  const int w = tid >> 6, lane = tid & 63, n = lane & 15, q = lane >> 4;
  const int base = blockIdx.x * 64;

  for (int i = tid; i < 1536; i += 256) {
    int t = i / 24, jj = i - t * 24;
    s_tile[t * 26 + jj] = s_in[(size_t)base * 24 + i];
  }

  // Q fragments (64 tokens, B-operand layout) straight from global pc
  bf16x8 qf[4][4];                     // [tok-tile][ks]
  #pragma unroll
  for (int tt = 0; tt < 4; ++tt)
    #pragma unroll
    for (int ks = 0; ks < 4; ++ks) {
      const float4* qp = (const float4*)(pc + (size_t)(base + tt * 16 + n) * 128 + ks * 32 + q * 8);
      float4 x = qp[0], y = qp[1];
      bf16x8 a;
      a[0] = (bf16_t)x.x; a[1] = (bf16_t)x.y; a[2] = (bf16_t)x.z; a[3] = (bf16_t)x.w;
      a[4] = (bf16_t)y.x; a[5] = (bf16_t)y.y; a[6] = (bf16_t)y.z; a[7] = (bf16_t)y.w;
      qf[tt][ks] = a;
    }

  f32x4 o[4][2];                       // [tok-tile][f-tile], f = w*32 + ft*16 + n
  #pragma unroll
  for (int tt = 0; tt < 4; ++tt) {
    o[tt][0] = (f32x4){0.f, 0.f, 0.f, 0.f};
    o[tt][1] = (f32x4){0.f, 0.f, 0.f, 0.f};
  }
  float l_acc[4] = {0.f, 0.f, 0.f, 0.f};

  const u16* mT_frag = mTp + (size_t)(w * 4) * 512 + lane * 8;   // + (j*16 + ks)*512
  const u16* mF_frag = mFp + (size_t)(w * 2) * 512 + lane * 8;   // + (j*16 + h*8 + ft)*512

  const float invs = 0.088388347648318447f; // 1/sqrt(128)
  __syncthreads();                          // s_tile ready

  for (int j = 0; j < 24; ++j) {
    // S^T tile: this wave owns slots [w*16, w*16+16) x 64 tokens
    f32x4 sacc[4];
    #pragma unroll
    for (int tt = 0; tt < 4; ++tt) sacc[tt] = (f32x4){0.f, 0.f, 0.f, 0.f};
    #pragma unroll
    for (int ks = 0; ks < 4; ++ks) {
      bf16x8 am = *(const bf16x8*)(mT_frag + (size_t)(j * 16 + ks) * 512);
      #pragma unroll
      for (int tt = 0; tt < 4; ++tt)
        sacc[tt] = MFMA16(am, qf[tt][ks], sacc[tt], 0, 0, 0);
    }

    __syncthreads();   // previous chunk's PV reads of Pl are done
    #pragma unroll
    for (int tt = 0; tt < 4; ++tt) {
      float sj = s_tile[(tt * 16 + n) * 26 + j] * invs;
      float p0 = __expf(sacc[tt][0] * sj);
      float p1 = __expf(sacc[tt][1] * sj);
      float p2 = __expf(sacc[tt][2] * sj);
      float p3 = __expf(sacc[tt][3] * sj);
      l_acc[tt] += (p0 + p1) + (p2 + p3);
      ushort4 pk;
      pk.x = f2bf(p0); pk.y = f2bf(p1); pk.z = f2bf(p2); pk.w = f2bf(p3);
      *(ushort4*)(&Pl[(tt * 16 + n) * 72 + w * 16 + q * 4]) = pk;
    }
    __syncthreads();   // P visible to all waves

    // PV: this wave owns f in [w*32, w*32+32) x 64 tokens
    #pragma unroll
    for (int h = 0; h < 2; ++h) {
      bf16x8 bm[2];
      #pragma unroll
      for (int ft = 0; ft < 2; ++ft)
        bm[ft] = *(const bf16x8*)(mF_frag + (size_t)(j * 16 + h * 8 + ft) * 512);
      #pragma unroll
      for (int tt = 0; tt < 4; ++tt) {
        bf16x8 pa = *(const bf16x8*)(&Pl[(tt * 16 + n) * 72 + h * 32 + q * 8]);
        o[tt][0] = MFMA16(pa, bm[0], o[tt][0], 0, 0, 0);
        o[tt][1] = MFMA16(pa, bm[1], o[tt][1], 0, 0, 0);
      }
    }
  }

  // l reduction: per-wave partials (sum over q) -> LDS -> sum over waves
  #pragma unroll
  for (int tt = 0; tt < 4; ++tt) {
    float v = l_acc[tt];
    v += __shfl_xor(v, 16, 64);
    v += __shfl_xor(v, 32, 64);
    if (q == 0) lw[w * 64 + tt * 16 + n] = v;
  }
  __syncthreads();

  // epilogue: rec = O/l, loss partial, per-f max
  float lsum = 0.f;
  float fmax2[2] = {-__builtin_inff(), -__builtin_inff()};
  #pragma unroll
  for (int tt = 0; tt < 4; ++tt) {
    f32x4 linv;
    #pragma unroll
    for (int r = 0; r < 4; ++r) {
      int tok = tt * 16 + q * 4 + r;
      float lt = lw[tok] + lw[64 + tok] + lw[128 + tok] + lw[192 + tok];
      linv[r] = 1.f / lt;
    }
    #pragma unroll
    for (int ft = 0; ft < 2; ++ft)
      #pragma unroll
      for (int r = 0; r < 4; ++r) {
        const int token = base + tt * 16 + q * 4 + r;
        const int f = w * 32 + ft * 16 + n;
        float rec = o[tt][ft][r] * linv[r];
        float d = rec - pc[(size_t)token * 128 + f];
        lsum += d * d;
        fmax2[ft] = fmaxf(fmax2[ft], rec);
      }
  }
  #pragma unroll
  for (int ft = 0; ft < 2; ++ft) {
    float v = fmax2[ft];
    v = fmaxf(v, __shfl_xor(v, 16, 64));
    v = fmaxf(v, __shfl_xor(v, 32, 64));
    if (q == 0) atomic_max_f32(&skl[(base / NT_TOK) * 128 + w * 32 + ft * 16 + n], v);
  }
  #pragma unroll
  for (int d2 = 1; d2 < 64; d2 <<= 1) lsum += __shfl_xor(lsum, d2, 64);
  if (lane == 0) redL[w] = lsum;
  __syncthreads();
  if (tid == 0) atomicAdd(loss, redL[0] + redL[1] + redL[2] + redL[3]);
}

// ---------------- head: LN -> Linear -> GELU -> Linear + loss finalize -----
__global__ void k_head(const float* __restrict__ skl,
                       const float* __restrict__ ln_g, const float* __restrict__ ln_b,
                       const float* __restrict__ w1, const float* __restrict__ b1,
                       const float* __restrict__ w2, const float* __restrict__ b2,
                       const float* __restrict__ loss, float* __restrict__ out)
{
  __shared__ float hbuf[128];
  __shared__ float gbuf[64];
  __shared__ float red[4];
  const int t = threadIdx.x;            // 128 threads
  const int ln = t & 63, wv = t >> 6;
  for (int b = 0; b < 4; ++b) {
    float x = skl[b * 128 + t];
    float s1 = x, s2 = x * x;
    #pragma unroll
    for (int d = 1; d < 64; d <<= 1) {
      s1 += __shfl_xor(s1, d, 64);
      s2 += __shfl_xor(s2, d, 64);
    }
    if (ln == 0) { red[wv * 2] = s1; red[wv * 2 + 1] = s2; }
    __syncthreads();
    float mu = (red[0] + red[2]) * (1.f / 128.f);
    float var = (red[1] + red[3]) * (1.f / 128.f) - mu * mu;
    float hn = (x - mu) * rsqrtf(var + 1e-5f) * ln_g[t] + ln_b[t];
    hbuf[t] = hn;
    __syncthreads();
    if (t < 64) {
      float a = b1[t];
      for (int c = 0; c < 128; ++c) a += hbuf[c] * w1[t * 128 + c];
      gbuf[t] = 0.5f * a * (1.f + erff(a * 0.70710678118654752f));
    }
    __syncthreads();
    if (t < 72) {
      float a = b2[t];
      for (int c = 0; c < 64; ++c) a += gbuf[c] * w2[t * 64 + c];
      out[b * 72 + t] = a;
    }
    __syncthreads();
  }
  if (t == 0) out[1179936] = loss[0] * (1.f / 6291456.f);
}

extern "C" void kernel_launch(void* const* d_in, const int* in_sizes, int n_in,
                              void* d_out, int out_size, void* d_ws, size_t ws_size,
                              hipStream_t stream) {
  (void)in_sizes; (void)n_in; (void)out_size; (void)ws_size;
  const float* feat  = (const float*)d_in[0];
  const float* seg_w = (const float*)d_in[1];
  const float* seg_b = (const float*)d_in[2];
  const float* pc_w  = (const float*)d_in[3];
  const float* pc_b  = (const float*)d_in[4];
  const float* mem   = (const float*)d_in[5];
  const float* ln_g  = (const float*)d_in[6];
  const float* ln_b  = (const float*)d_in[7];
  const float* w1    = (const float*)d_in[8];
  const float* b1    = (const float*)d_in[9];
  const float* w2    = (const float*)d_in[10];
  const float* b2    = (const float*)d_in[11];

  char* ws = (char*)d_ws;
  float* pc_buf = (float*)(ws + WS_PC);
  float* s_buf  = (float*)(ws + WS_S);
  u16*   Wp     = (u16*)(ws + WS_WP);
  u16*   mTp    = (u16*)(ws + WS_MTP);
  u16*   mFp    = (u16*)(ws + WS_MFP);
  float* sklb   = (float*)(ws + WS_SKL);
  float* lossb  = (float*)(ws + WS_LOSS);
  float* out    = (float*)d_out;

  k_init<<<275, 256, 0, stream>>>(seg_w, pc_w, mem, Wp, mTp, mFp, sklb, lossb);
  k_proj<<<768, 256, 0, stream>>>(feat, Wp, seg_b, pc_b, pc_buf, s_buf, out + 288);
  k_attn<<<768, 256, 0, stream>>>(pc_buf, s_buf, mFp, mTp, sklb, lossb);
  k_head<<<1, 128, 0, stream>>>(sklb, ln_g, ln_b, w1, b1, w2, b2, lossb, out);
}